// Round 1
// baseline (296.277 us; speedup 1.0000x reference)
//
#include <hip/hip_runtime.h>

// SNN 2048->2048->2048->512, T=100, batch 32, LIF.
// Per layer: big GEMM over all t (M=3200=T*32) + sequential LIF scan.
// 7 stream-ordered launches, no grid sync.
//
// Unified "octet-blocked" layout (pitch MTOT) for spikes AND I:
//   half_idx(v, m) = ((v>>3)*MTOT + m)*8 + (v&7)     v = feature index
// Wave B-frag load at ((kb*4+quad)*MTOT + m0+mi)*8 yields
//   B[k=kb*32+quad*8+j][n=m0+mi]   (proven rounds 6-9).
//
// ws regions (total 39,321,600 B -- PROVEN available in round 7):
//   R0 [0,13107200) | R1 [+13107200) | I [+26214400)
// Schedule (region liveness verified):
//   fuse{enc->R0, convW0->R1} | gemm0(R1,R0->I) | fuse{scan0 I->R1, convW1->R0}
//   | gemm1(R0,R1->I) | fuse{scan1 I->R0, convW2->R1} | gemm2(R1,R0->I)
//   | scan2(I->out)
//
// R10 GEMM changes (theory: latency-bound, 22% MFMA slots wasted):
//   - balanced tile assignment: wave w gets cnt in {TPW-1, TPW} tiles
//     (rem = jcount - 16*(TPW-1)); invalid slots execute NO MFMAs
//     (was: val[u] gated only the store; 14/64 slots = 22% wasted MFMA).
//   - explicit depth-2 B prefetch (kb+2, kb+3 in flight while computing
//     kb, kb+1) with compile-time register indexing.
//   - kb=0/1 B preloads issued BEFORE the A-staging __syncthreads (the
//     barrier's vmcnt(0) drain completes them under the 128KB A copy).
#define T_STEPS 100
#define MTOT    3200
#define R0_OFF  0
#define R1_OFF  13107200
#define I_OFF   26214400

typedef _Float16 half8_t __attribute__((ext_vector_type(8)));
typedef _Float16 half4_t __attribute__((ext_vector_type(4)));
typedef float    f32x4   __attribute__((ext_vector_type(4)));

// ---------------- encode (device fn): Poisson spikes for all t ----------
__device__ __forceinline__ void encode_body(
    int blk, const float* __restrict__ x, const float* __restrict__ noise,
    _Float16* __restrict__ spk0, float* __restrict__ out)
{
    if (blk == 0 && threadIdx.x == 0) out[16384] = 0.0f;  // runs first
    const int tid = threadIdx.x;
    const int m0  = blk * 16;
    __shared__ half8_t lds[16 * 257];    // pad: store-phase reads conflict-free
    #pragma unroll
    for (int ml = 0; ml < 16; ++ml) {    // read phase: thread = feature octet
        const int m = m0 + ml;
        const int t = m >> 5, b = m & 31;
        const float4 x1 = *(const float4*)(x + b * 2048 + tid * 8);
        const float4 x2 = *(const float4*)(x + b * 2048 + tid * 8 + 4);
        const float4 n1 = *(const float4*)(noise + (size_t)t * 65536 + b * 2048 + tid * 8);
        const float4 n2 = *(const float4*)(noise + (size_t)t * 65536 + b * 2048 + tid * 8 + 4);
        const float xr[8] = {x1.x,x1.y,x1.z,x1.w,x2.x,x2.y,x2.z,x2.w};
        const float nz[8] = {n1.x,n1.y,n1.z,n1.w,n2.x,n2.y,n2.z,n2.w};
        half8_t sp;
        #pragma unroll
        for (int j = 0; j < 8; ++j) {
            const float r = fminf(fmaxf(xr[j], 0.0f), 1.0f);
            sp[j] = (nz[j] < r) ? (_Float16)1.0f : (_Float16)0.0f;
        }
        lds[ml * 257 + tid] = sp;
    }
    __syncthreads();
    #pragma unroll
    for (int r = 0; r < 16; ++r) {       // store phase: lanes = consecutive m
        const int ml  = tid & 15;
        const int oct = r * 16 + (tid >> 4);
        *(half8_t*)(spk0 + ((size_t)oct * MTOT + m0 + ml) * 8) = lds[ml * 257 + oct];
    }
}

// ------------- convw (device fn): W fp32 -> fp16 A-frag swizzled ---------
// Wf[(row>>4)*32768 + ((koct>>2)*64 + (koct&3)*16 + (row&15))*8 + j]
//   = W[row][koct*8+j];  8 rows per block.
__device__ __forceinline__ void convw_body(
    int blk, const float* __restrict__ W, _Float16* __restrict__ Wf)
{
    const int koct = threadIdx.x;        // 0..255
    #pragma unroll
    for (int r = 0; r < 8; ++r) {
        const int row = blk * 8 + r;
        const float* wp = W + (size_t)row * 2048 + koct * 8;
        const float4 f1 = *(const float4*)(wp);
        const float4 f2 = *(const float4*)(wp + 4);
        half8_t h = {(_Float16)f1.x,(_Float16)f1.y,(_Float16)f1.z,(_Float16)f1.w,
                     (_Float16)f2.x,(_Float16)f2.y,(_Float16)f2.z,(_Float16)f2.w};
        const size_t idx = (size_t)(row >> 4) * 32768
                         + ((size_t)((koct >> 2) * 64 + (koct & 3) * 16 + (row & 15))) * 8;
        *(half8_t*)(Wf + idx) = h;
    }
}

// ------------- scan (device fn): LIF, sequential t, parallel (n,b) -------
__device__ __forceinline__ void scan_body(
    int blk, const _Float16* __restrict__ I, const float* __restrict__ bias,
    _Float16* __restrict__ spk_out, float* __restrict__ out,
    const int nshift, const int is_last)
{
    const int gid = blk * 256 + threadIdx.x;     // [0, 32<<nshift)
    const int N = 1 << nshift;
    const int n = gid & (N - 1);
    const int b = gid >> nshift;
    const float bi = bias[n];
    const size_t nbase = (size_t)(n >> 3) * (MTOT * 8) + (n & 7);
    float mem = 0.f, syn = 0.f, osum = 0.f, cnt = 0.f;
    #pragma unroll 4
    for (int t = 0; t < T_STEPS; ++t) {
        const int m = t * 32 + b;
        const float Iv = (float)I[nbase + (size_t)m * 8] + bi;
        syn = syn + (-syn / 5.0f + Iv);
        mem = mem + (-mem / 20.0f + syn);
        const float sv = (mem >= 1.0f) ? 1.0f : 0.0f;
        mem = (sv != 0.0f) ? 0.0f : mem;       // reset
        mem = (mem > 0.0f) ? mem : 0.0f;       // clamp negatives
        cnt += sv; osum += sv;
        if (!is_last) spk_out[nbase + (size_t)m * 8] = (_Float16)sv;
    }
    if (is_last) out[b * 512 + n] = osum * 0.01f;    // mean over T
    float c = cnt;
    #pragma unroll
    for (int s2 = 1; s2 < 64; s2 <<= 1) c += __shfl_xor(c, s2);
    if ((threadIdx.x & 63) == 0) atomicAdd(&out[16384], c);
}

// ---------------- fused small kernels (all 256 thr) ----------------
__global__ __launch_bounds__(256, 2) void snn_enc_convw_kernel(
    const float* __restrict__ x, const float* __restrict__ noise,
    _Float16* __restrict__ spk0, float* __restrict__ out,
    const float* __restrict__ W, _Float16* __restrict__ Wf)
{
    if (blockIdx.x < 200) encode_body(blockIdx.x, x, noise, spk0, out);
    else                  convw_body(blockIdx.x - 200, W, Wf);
}

__global__ __launch_bounds__(256, 4) void snn_scan_convw_kernel(
    const _Float16* __restrict__ I, const float* __restrict__ bias,
    _Float16* __restrict__ spk_out, float* __restrict__ out,
    const int scan_blocks, const int nshift,
    const float* __restrict__ W, _Float16* __restrict__ Wf)
{
    if ((int)blockIdx.x < scan_blocks)
        scan_body(blockIdx.x, I, bias, spk_out, out, nshift, 0);
    else
        convw_body(blockIdx.x - scan_blocks, W, Wf);
}

__global__ __launch_bounds__(256, 4) void snn_scan_kernel(
    const _Float16* __restrict__ I, const float* __restrict__ bias,
    float* __restrict__ out, const int nshift)
{
    scan_body(blockIdx.x, I, bias, nullptr, out, nshift, 1);
}

// ---------------- GEMM: I = spk @ W^T (fp16 MFMA 16x16x32) ----------------
// Block: 32 N-rows (two A subtiles, 128KB LDS), 1024 thr = 16 waves.
// Wave: NT m-tiles (NT in {TPW-1, TPW}, balanced) x 2 n-subtiles.
// Depth-2 B prefetch: while computing kb,kb+1, loads for kb+2,kb+3 in flight.
// Each B load feeds 2 MFMAs. Grid: nbb x NC chunks, chunk aligns with XCD.

template<int NT, int TPW>
__device__ __forceinline__ void gemm_tiles(
    const _Float16* __restrict__ wlds, _Float16* __restrict__ I,
    const _Float16* const (&bp)[TPW], const int (&mt)[TPW],
    half8_t (&pre0)[TPW], half8_t (&pre1)[TPW],
    const int row_base, const int lane)
{
    const int quad = lane >> 4, mi = lane & 15;
    f32x4 acc[NT][2];
    #pragma unroll
    for (int u = 0; u < NT; ++u) { acc[u][0] = (f32x4){0,0,0,0}; acc[u][1] = (f32x4){0,0,0,0}; }

    half8_t bc0[NT], bc1[NT];           // B frags for kb (even) / kb+1 (odd)
    #pragma unroll
    for (int u = 0; u < NT; ++u) { bc0[u] = pre0[u]; bc1[u] = pre1[u]; }

    #pragma unroll 2
    for (int kb = 0; kb < 64; kb += 2) {
        half8_t bn0[NT], bn1[NT];
        if (kb < 62) {                   // issue kb+2 loads before even MFMAs
            const size_t kn0 = (size_t)((kb + 2) * 4 + quad) * (MTOT * 8);
            #pragma unroll
            for (int u = 0; u < NT; ++u) bn0[u] = *(const half8_t*)(bp[u] + kn0);
        }
        const half8_t a00 = *(const half8_t*)(wlds + ((size_t)(kb * 64 + lane)) * 8);
        const half8_t a01 = *(const half8_t*)(wlds + 32768 + ((size_t)(kb * 64 + lane)) * 8);
        #pragma unroll
        for (int u = 0; u < NT; ++u) {
            acc[u][0] = __builtin_amdgcn_mfma_f32_16x16x32_f16(a00, bc0[u], acc[u][0], 0, 0, 0);
            acc[u][1] = __builtin_amdgcn_mfma_f32_16x16x32_f16(a01, bc0[u], acc[u][1], 0, 0, 0);
        }
        if (kb < 62) {                   // issue kb+3 loads before odd MFMAs
            const size_t kn1 = (size_t)((kb + 3) * 4 + quad) * (MTOT * 8);
            #pragma unroll
            for (int u = 0; u < NT; ++u) bn1[u] = *(const half8_t*)(bp[u] + kn1);
        }
        const half8_t a10 = *(const half8_t*)(wlds + ((size_t)((kb + 1) * 64 + lane)) * 8);
        const half8_t a11 = *(const half8_t*)(wlds + 32768 + ((size_t)((kb + 1) * 64 + lane)) * 8);
        #pragma unroll
        for (int u = 0; u < NT; ++u) {
            acc[u][0] = __builtin_amdgcn_mfma_f32_16x16x32_f16(a10, bc1[u], acc[u][0], 0, 0, 0);
            acc[u][1] = __builtin_amdgcn_mfma_f32_16x16x32_f16(a11, bc1[u], acc[u][1], 0, 0, 0);
        }
        if (kb < 62) {
            #pragma unroll
            for (int u = 0; u < NT; ++u) { bc0[u] = bn0[u]; bc1[u] = bn1[u]; }
        }
    }
    // store: C row(n)=quad*4+r, col(m)=mi -> octet-blocked I
    #pragma unroll
    for (int s = 0; s < 2; ++s) {
        const int n0 = row_base + s * 16 + quad * 4;
        const size_t obase = (size_t)(n0 >> 3) * (MTOT * 8) + (n0 & 7);
        #pragma unroll
        for (int u = 0; u < NT; ++u) {
            half4_t h;
            #pragma unroll
            for (int r = 0; r < 4; ++r) h[r] = (_Float16)acc[u][s][r];
            *(half4_t*)(I + obase + (size_t)(mt[u] * 16 + mi) * 8) = h;
        }
    }
}

// Requires: jcount in (16*(TPW-1), 16*TPW]  (single pass over tiles).
//   gemm0/1: NC=4  -> jcount=50 in (48,64], TPW=4, rem=2.
//   gemm2:   NC=16 -> jcount=12..13 in (0,16], TPW=1.
template<int NC, int TPW>
__global__ __launch_bounds__(1024, 4) void snn_gemm_kernel(
    const _Float16* __restrict__ Wf, const _Float16* __restrict__ spk,
    _Float16* __restrict__ I)
{
    const int tid  = threadIdx.x;
    const int lane = tid & 63;
    const int w    = tid >> 6;            // wave 0..15
    const int mi   = lane & 15;
    const int quad = lane >> 4;
    const int chunk = blockIdx.x % NC;
    const int nbb   = blockIdx.x / NC;
    const int row_base = nbb * 32;
    const int jcount = (200 - chunk + NC - 1) / NC;   // 16-m-tiles in chunk
    const int rem    = jcount - 16 * (TPW - 1);       // waves getting TPW tiles
    const int cnt      = (w < rem) ? TPW : (TPW - 1);
    const int jl_start = w * (TPW - 1) + ((w < rem) ? w : rem);

    int mt[TPW]; const _Float16* bp[TPW];
    #pragma unroll
    for (int u = 0; u < TPW; ++u) {
        int jl = jl_start + u; if (jl > jcount - 1) jl = jcount - 1;  // clamp (unused slots)
        mt[u] = chunk + NC * jl;
        bp[u] = spk + ((size_t)mt[u] * 16 + mi) * 8;
    }
    // kb=0/1 B preloads BEFORE the barrier: completed for free by the
    // vmcnt(0) drain that __syncthreads performs after A staging.
    half8_t pre0[TPW], pre1[TPW];
    #pragma unroll
    for (int u = 0; u < TPW; ++u) pre0[u] = *(const half8_t*)(bp[u] + (size_t)quad * (MTOT * 8));
    #pragma unroll
    for (int u = 0; u < TPW; ++u) pre1[u] = *(const half8_t*)(bp[u] + (size_t)(4 + quad) * (MTOT * 8));

    __shared__ _Float16 wlds[32 * 2048];              // 128 KB, A-frag order
    {   // contiguous copy: Wf 16-row groups 2*nbb, 2*nbb+1
        const half8_t* __restrict__ src = (const half8_t*)(Wf + (size_t)nbb * 65536);
        half8_t* __restrict__ dst = (half8_t*)wlds;
        #pragma unroll
        for (int r = 0; r < 8; ++r) dst[tid + r * 1024] = src[tid + r * 1024];
    }
    __syncthreads();

    if (cnt == TPW) {
        gemm_tiles<TPW, TPW>(wlds, I, bp, mt, pre0, pre1, row_base, lane);
    } else if constexpr (TPW >= 2) {
        gemm_tiles<TPW - 1, TPW>(wlds, I, bp, mt, pre0, pre1, row_base, lane);
    }
    // TPW==1 && cnt==0: wave has no tile, done.
}

extern "C" void kernel_launch(void* const* d_in, const int* in_sizes, int n_in,
                              void* d_out, int out_size, void* d_ws, size_t ws_size,
                              hipStream_t stream) {
    // setup_inputs() dict order: x, noise, time_steps, W0, b0, W1, b1, W2, b2
    const float* x     = (const float*)d_in[0];
    const float* noise = (const float*)d_in[1];
    const float* W0 = (const float*)d_in[3];
    const float* b0 = (const float*)d_in[4];
    const float* W1 = (const float*)d_in[5];
    const float* b1 = (const float*)d_in[6];
    const float* W2 = (const float*)d_in[7];
    const float* b2 = (const float*)d_in[8];
    float* out = (float*)d_out;

    _Float16* R0 = (_Float16*)((char*)d_ws + R0_OFF);
    _Float16* R1 = (_Float16*)((char*)d_ws + R1_OFF);
    _Float16* Ib = (_Float16*)((char*)d_ws + I_OFF);

    // encode -> R0 ; convW0 -> R1
    snn_enc_convw_kernel<<<dim3(456), dim3(256), 0, stream>>>(x, noise, R0, out, W0, R1);
    // gemm0: 64 nbb x 4 chunks = 256 blocks
    snn_gemm_kernel<4, 4><<<dim3(256), dim3(1024), 0, stream>>>(R1, R0, Ib);
    // scan0 (I->R1, 256 blocks) ; convW1 -> R0 (256 blocks)
    snn_scan_convw_kernel<<<dim3(512), dim3(256), 0, stream>>>(Ib, b0, R1, out, 256, 11, W1, R0);
    // gemm1
    snn_gemm_kernel<4, 4><<<dim3(256), dim3(1024), 0, stream>>>(R0, R1, Ib);
    // scan1 (I->R0, 256 blocks) ; convW2 -> R1 (64 blocks)
    snn_scan_convw_kernel<<<dim3(320), dim3(256), 0, stream>>>(Ib, b1, R0, out, 256, 11, W2, R1);
    // gemm2: 16 nbb x 16 chunks = 256 blocks, 1 tile/wave
    snn_gemm_kernel<16, 1><<<dim3(256), dim3(1024), 0, stream>>>(R1, R0, Ib);
    // scan2 -> out
    snn_scan_kernel<<<dim3(64), dim3(256), 0, stream>>>(Ib, b2, out, 9);

    (void)in_sizes; (void)n_in; (void)out_size; (void)ws_size;
}

// Round 2
// 275.506 us; speedup vs baseline: 1.0754x; 1.0754x over previous
//
#include <hip/hip_runtime.h>

// SNN 2048->2048->2048->512, T=100, batch 32, LIF.
// Per layer: big GEMM over all t (M=3200=T*32) + sequential LIF scan.
// 7 stream-ordered launches, no grid sync.
//
// Unified "octet-blocked" layout (pitch MTOT) for spikes AND I:
//   half_idx(v, m) = ((v>>3)*MTOT + m)*8 + (v&7)     v = feature index
// Wave B-frag load at ((kb*4+quad)*MTOT + m0+mi)*8 yields
//   B[k=kb*32+quad*8+j][n=m0+mi]   (proven rounds 6-9).
//
// ws regions (total 39,321,600 B -- PROVEN available in round 7):
//   R0 [0,13107200) | R1 [+13107200) | I [+26214400)
// Schedule (region liveness verified):
//   fuse{enc->R0, convW0->R1} | gemm0(R1,R0->I) | fuse{scan0 I->R1, convW1->R0}
//   | gemm1(R0,R1->I) | fuse{scan1 I->R0, convW2->R1} | gemm2(R1,R0->I)
//   | scan2(I->out)
//
// R11: gemm0/1 restructured to 64-row blocks (theory: L2 B-traffic bound).
//   - 4 A-subtiles per block: each B-load feeds 4 MFMAs -> B L2 traffic
//     halved (838 -> 419 MB); A staged in two sequential K-halves (128 KB
//     LDS each, Wf group layout is K-half contiguous). acc carries across.
//   - NC=8: chunk == XCD (blk%8), per-XCD-resident chunk B = 1.64 MB.
//   - depth-2 B prefetch via two NAMED reg sets (reload-after-use, zero
//     copies -- reverts R10's VALU overhead which regressed).
//   - gemm2 reverted to proven R9 32-row kernel.
#define T_STEPS 100
#define MTOT    3200
#define R0_OFF  0
#define R1_OFF  13107200
#define I_OFF   26214400

typedef _Float16 half8_t __attribute__((ext_vector_type(8)));
typedef _Float16 half4_t __attribute__((ext_vector_type(4)));
typedef float    f32x4   __attribute__((ext_vector_type(4)));

// ---------------- encode (device fn): Poisson spikes for all t ----------
__device__ __forceinline__ void encode_body(
    int blk, const float* __restrict__ x, const float* __restrict__ noise,
    _Float16* __restrict__ spk0, float* __restrict__ out)
{
    if (blk == 0 && threadIdx.x == 0) out[16384] = 0.0f;  // runs first
    const int tid = threadIdx.x;
    const int m0  = blk * 16;
    __shared__ half8_t lds[16 * 257];    // pad: store-phase reads conflict-free
    #pragma unroll
    for (int ml = 0; ml < 16; ++ml) {    // read phase: thread = feature octet
        const int m = m0 + ml;
        const int t = m >> 5, b = m & 31;
        const float4 x1 = *(const float4*)(x + b * 2048 + tid * 8);
        const float4 x2 = *(const float4*)(x + b * 2048 + tid * 8 + 4);
        const float4 n1 = *(const float4*)(noise + (size_t)t * 65536 + b * 2048 + tid * 8);
        const float4 n2 = *(const float4*)(noise + (size_t)t * 65536 + b * 2048 + tid * 8 + 4);
        const float xr[8] = {x1.x,x1.y,x1.z,x1.w,x2.x,x2.y,x2.z,x2.w};
        const float nz[8] = {n1.x,n1.y,n1.z,n1.w,n2.x,n2.y,n2.z,n2.w};
        half8_t sp;
        #pragma unroll
        for (int j = 0; j < 8; ++j) {
            const float r = fminf(fmaxf(xr[j], 0.0f), 1.0f);
            sp[j] = (nz[j] < r) ? (_Float16)1.0f : (_Float16)0.0f;
        }
        lds[ml * 257 + tid] = sp;
    }
    __syncthreads();
    #pragma unroll
    for (int r = 0; r < 16; ++r) {       // store phase: lanes = consecutive m
        const int ml  = tid & 15;
        const int oct = r * 16 + (tid >> 4);
        *(half8_t*)(spk0 + ((size_t)oct * MTOT + m0 + ml) * 8) = lds[ml * 257 + oct];
    }
}

// ------------- convw (device fn): W fp32 -> fp16 A-frag swizzled ---------
// Wf[(row>>4)*32768 + ((koct>>2)*64 + (koct&3)*16 + (row&15))*8 + j]
//   = W[row][koct*8+j];  8 rows per block.
__device__ __forceinline__ void convw_body(
    int blk, const float* __restrict__ W, _Float16* __restrict__ Wf)
{
    const int koct = threadIdx.x;        // 0..255
    #pragma unroll
    for (int r = 0; r < 8; ++r) {
        const int row = blk * 8 + r;
        const float* wp = W + (size_t)row * 2048 + koct * 8;
        const float4 f1 = *(const float4*)(wp);
        const float4 f2 = *(const float4*)(wp + 4);
        half8_t h = {(_Float16)f1.x,(_Float16)f1.y,(_Float16)f1.z,(_Float16)f1.w,
                     (_Float16)f2.x,(_Float16)f2.y,(_Float16)f2.z,(_Float16)f2.w};
        const size_t idx = (size_t)(row >> 4) * 32768
                         + ((size_t)((koct >> 2) * 64 + (koct & 3) * 16 + (row & 15))) * 8;
        *(half8_t*)(Wf + idx) = h;
    }
}

// ------------- scan (device fn): LIF, sequential t, parallel (n,b) -------
__device__ __forceinline__ void scan_body(
    int blk, const _Float16* __restrict__ I, const float* __restrict__ bias,
    _Float16* __restrict__ spk_out, float* __restrict__ out,
    const int nshift, const int is_last)
{
    const int gid = blk * 256 + threadIdx.x;     // [0, 32<<nshift)
    const int N = 1 << nshift;
    const int n = gid & (N - 1);
    const int b = gid >> nshift;
    const float bi = bias[n];
    const size_t nbase = (size_t)(n >> 3) * (MTOT * 8) + (n & 7);
    float mem = 0.f, syn = 0.f, osum = 0.f, cnt = 0.f;
    #pragma unroll 4
    for (int t = 0; t < T_STEPS; ++t) {
        const int m = t * 32 + b;
        const float Iv = (float)I[nbase + (size_t)m * 8] + bi;
        syn = syn + (-syn / 5.0f + Iv);
        mem = mem + (-mem / 20.0f + syn);
        const float sv = (mem >= 1.0f) ? 1.0f : 0.0f;
        mem = (sv != 0.0f) ? 0.0f : mem;       // reset
        mem = (mem > 0.0f) ? mem : 0.0f;       // clamp negatives
        cnt += sv; osum += sv;
        if (!is_last) spk_out[nbase + (size_t)m * 8] = (_Float16)sv;
    }
    if (is_last) out[b * 512 + n] = osum * 0.01f;    // mean over T
    float c = cnt;
    #pragma unroll
    for (int s2 = 1; s2 < 64; s2 <<= 1) c += __shfl_xor(c, s2);
    if ((threadIdx.x & 63) == 0) atomicAdd(&out[16384], c);
}

// ---------------- fused small kernels (all 256 thr) ----------------
__global__ __launch_bounds__(256, 2) void snn_enc_convw_kernel(
    const float* __restrict__ x, const float* __restrict__ noise,
    _Float16* __restrict__ spk0, float* __restrict__ out,
    const float* __restrict__ W, _Float16* __restrict__ Wf)
{
    if (blockIdx.x < 200) encode_body(blockIdx.x, x, noise, spk0, out);
    else                  convw_body(blockIdx.x - 200, W, Wf);
}

__global__ __launch_bounds__(256, 4) void snn_scan_convw_kernel(
    const _Float16* __restrict__ I, const float* __restrict__ bias,
    _Float16* __restrict__ spk_out, float* __restrict__ out,
    const int scan_blocks, const int nshift,
    const float* __restrict__ W, _Float16* __restrict__ Wf)
{
    if ((int)blockIdx.x < scan_blocks)
        scan_body(blockIdx.x, I, bias, spk_out, out, nshift, 0);
    else
        convw_body(blockIdx.x - scan_blocks, W, Wf);
}

__global__ __launch_bounds__(256, 4) void snn_scan_kernel(
    const _Float16* __restrict__ I, const float* __restrict__ bias,
    float* __restrict__ out, const int nshift)
{
    scan_body(blockIdx.x, I, bias, nullptr, out, nshift, 1);
}

// ================= 64-row GEMM (gemm0/1): I = spk @ W^T =================
// Block: 64 N-rows (4 A subtiles), 1024 thr = 16 waves, LDS 128 KB holds
// one K-half of A. Each B-load (16B/lane) feeds 4 MFMAs. NC=8 chunks,
// chunk == XCD. jcount=25 -> waves get {2 (w<9), 1} tiles, balanced.

__device__ __forceinline__ half8_t ldB(const _Float16* __restrict__ p, int kq) {
    return *(const half8_t*)(p + (size_t)kq * (MTOT * 8));
}

// One K-half (32 kb steps). KB = 0 or 32 (global kb base). No barriers.
// bE/bO: two named B-frag sets, reload-after-use (depth ~2 kb, zero copies).
// Tail loads of the NEXT half (kb 32,33) are issued at KB=0's last step and
// stay in flight across the restage barriers.
template<bool HAS2, int KB>
__device__ __forceinline__ void gemm64_half(
    const _Float16* __restrict__ wlds,
    const _Float16* const (&bp)[2],
    half8_t (&bE)[2], half8_t (&bO)[2],
    f32x4 (&acc)[2][4],
    const int lane, const int quad)
{
    #pragma unroll 2
    for (int kbl = 0; kbl < 32; kbl += 2) {
        // ---- even k-step: kb = KB + kbl, B frags in bE ----
        half8_t a[4];
        #pragma unroll
        for (int s = 0; s < 4; ++s)
            a[s] = *(const half8_t*)(wlds + (size_t)s * 16384 + (size_t)(kbl * 64 + lane) * 8);
        #pragma unroll
        for (int s = 0; s < 4; ++s) {
            acc[0][s] = __builtin_amdgcn_mfma_f32_16x16x32_f16(a[s], bE[0], acc[0][s], 0, 0, 0);
            if (HAS2)
                acc[1][s] = __builtin_amdgcn_mfma_f32_16x16x32_f16(a[s], bE[1], acc[1][s], 0, 0, 0);
        }
        if (KB + kbl + 2 < 64) {                 // reload bE <- kb+2
            const int kq = (KB + kbl + 2) * 4 + quad;
            bE[0] = ldB(bp[0], kq);
            if (HAS2) bE[1] = ldB(bp[1], kq);
        }
        // ---- odd k-step: kb = KB + kbl + 1, B frags in bO ----
        half8_t c[4];
        #pragma unroll
        for (int s = 0; s < 4; ++s)
            c[s] = *(const half8_t*)(wlds + (size_t)s * 16384 + (size_t)((kbl + 1) * 64 + lane) * 8);
        #pragma unroll
        for (int s = 0; s < 4; ++s) {
            acc[0][s] = __builtin_amdgcn_mfma_f32_16x16x32_f16(c[s], bO[0], acc[0][s], 0, 0, 0);
            if (HAS2)
                acc[1][s] = __builtin_amdgcn_mfma_f32_16x16x32_f16(c[s], bO[1], acc[1][s], 0, 0, 0);
        }
        if (KB + kbl + 3 < 64) {                 // reload bO <- kb+3
            const int kq = (KB + kbl + 3) * 4 + quad;
            bO[0] = ldB(bp[0], kq);
            if (HAS2) bO[1] = ldB(bp[1], kq);
        }
    }
}

template<int NC>
__global__ __launch_bounds__(1024, 4) void snn_gemm64_kernel(
    const _Float16* __restrict__ Wf, const _Float16* __restrict__ spk,
    _Float16* __restrict__ I)
{
    const int tid  = threadIdx.x;
    const int lane = tid & 63;
    const int w    = tid >> 6;            // wave 0..15
    const int mi   = lane & 15;
    const int quad = lane >> 4;
    const int chunk = blockIdx.x % NC;    // == XCD for NC=8
    const int nbb   = blockIdx.x / NC;    // 0..31 (64-row groups)
    const int row_base = nbb * 64;
    const int jcount = (200 - chunk + NC - 1) / NC;   // 25 for NC=8
    const int rem    = jcount - 16;       // waves w<rem own 2 tiles
    const bool has2  = (w < rem);
    int jl_start = has2 ? (2 * w) : (w + (rem > 0 ? rem : 0));
    if (jl_start < 0) jl_start = 0;
    const bool active = jl_start < jcount;

    int mt[2]; const _Float16* bp[2];
    #pragma unroll
    for (int u = 0; u < 2; ++u) {
        int jl = jl_start + u;
        if (jl >= jcount) jl = jcount - 1;           // clamp (unused slots)
        mt[u] = chunk + NC * jl;
        bp[u] = spk + ((size_t)mt[u] * 16 + mi) * 8;
    }

    // kb=0/1 B preloads BEFORE the stage barrier: drained for free by the
    // barrier's vmcnt(0) while the 128 KB A copy is in flight.
    half8_t bE[2], bO[2];
    if (active) {
        bE[0] = ldB(bp[0], quad);
        bO[0] = ldB(bp[0], 4 + quad);
        if (has2) { bE[1] = ldB(bp[1], quad); bO[1] = ldB(bp[1], 4 + quad); }
    }

    __shared__ _Float16 wlds[65536];                 // 128 KB = one K-half
    const half8_t* __restrict__ wsrc = (const half8_t*)Wf;
    {   // stage K-half 0: groups 4nbb..4nbb+3, each group's first 32 KB
        half8_t* dst = (half8_t*)wlds;
        #pragma unroll
        for (int r = 0; r < 8; ++r) {
            const int flat = r * 1024 + tid;         // 16B units
            const int s = flat >> 11, off = flat & 2047;
            dst[flat] = wsrc[(size_t)(4 * nbb + s) * 4096 + off];
        }
    }
    __syncthreads();

    f32x4 acc[2][4];
    #pragma unroll
    for (int u = 0; u < 2; ++u) {
        #pragma unroll
        for (int s = 0; s < 4; ++s) acc[u][s] = (f32x4){0,0,0,0};
    }

    if (active) {
        if (has2) gemm64_half<true , 0>(wlds, bp, bE, bO, acc, lane, quad);
        else      gemm64_half<false, 0>(wlds, bp, bE, bO, acc, lane, quad);
    }
    __syncthreads();
    {   // stage K-half 1: each group's second 32 KB
        half8_t* dst = (half8_t*)wlds;
        #pragma unroll
        for (int r = 0; r < 8; ++r) {
            const int flat = r * 1024 + tid;
            const int s = flat >> 11, off = flat & 2047;
            dst[flat] = wsrc[(size_t)(4 * nbb + s) * 4096 + 2048 + off];
        }
    }
    __syncthreads();
    if (active) {
        if (has2) gemm64_half<true , 32>(wlds, bp, bE, bO, acc, lane, quad);
        else      gemm64_half<false, 32>(wlds, bp, bE, bO, acc, lane, quad);
    }

    // store: C row(n)=quad*4+r within subtile s, col(m)=mi -> octet-blocked I
    if (active) {
        #pragma unroll
        for (int s = 0; s < 4; ++s) {
            const int n0 = row_base + s * 16 + quad * 4;
            const size_t obase = (size_t)(n0 >> 3) * (MTOT * 8) + (n0 & 7);
            #pragma unroll
            for (int u = 0; u < 2; ++u) {
                if (u == 1 && !has2) continue;
                half4_t h;
                #pragma unroll
                for (int r = 0; r < 4; ++r) h[r] = (_Float16)acc[u][s][r];
                *(half4_t*)(I + obase + (size_t)(mt[u] * 16 + mi) * 8) = h;
            }
        }
    }
}

// ============== 32-row GEMM (gemm2, proven R9 version) ==================
template<int NC, int TPW>
__global__ __launch_bounds__(1024, 4) void snn_gemm_kernel(
    const _Float16* __restrict__ Wf, const _Float16* __restrict__ spk,
    _Float16* __restrict__ I)
{
    const int tid  = threadIdx.x;
    const int lane = tid & 63;
    const int w    = tid >> 6;            // wave 0..15
    const int quad = lane >> 4, mi = lane & 15;
    const int chunk = blockIdx.x % NC;
    const int nbb   = blockIdx.x / NC;
    const int row_base = nbb * 32;
    const int jcount = (200 - chunk + NC - 1) / NC;   // 16-m-tiles in chunk

    __shared__ _Float16 wlds[32 * 2048];              // 128 KB, A-frag order
    {   // contiguous copy: Wf 16-row groups 2*nbb, 2*nbb+1
        const half8_t* __restrict__ src = (const half8_t*)(Wf + (size_t)nbb * 65536);
        half8_t* __restrict__ dst = (half8_t*)wlds;
        #pragma unroll
        for (int r = 0; r < 8; ++r) dst[tid + r * 1024] = src[tid + r * 1024];
    }
    __syncthreads();

    for (int jl0 = TPW * w; jl0 < jcount; jl0 += 16 * TPW) {
        int mt[TPW]; bool val[TPW];
        const _Float16* bp[TPW];
        #pragma unroll
        for (int u = 0; u < TPW; ++u) {
            const int jl = jl0 + u;
            val[u] = jl < jcount;
            mt[u]  = chunk + NC * (val[u] ? jl : jl0);
            bp[u]  = spk + ((size_t)mt[u] * 16 + mi) * 8;
        }
        f32x4 acc[TPW][2];
        #pragma unroll
        for (int u = 0; u < TPW; ++u) { acc[u][0] = (f32x4){0,0,0,0}; acc[u][1] = (f32x4){0,0,0,0}; }

        half8_t bc[TPW];
        const size_t k0 = (size_t)quad * (MTOT * 8);
        #pragma unroll
        for (int u = 0; u < TPW; ++u) bc[u] = *(const half8_t*)(bp[u] + k0);

        #pragma unroll 4
        for (int kb = 0; kb < 64; ++kb) {
            half8_t bn[TPW];
            if (kb < 63) {
                const size_t kn = (size_t)((kb + 1) * 4 + quad) * (MTOT * 8);
                #pragma unroll
                for (int u = 0; u < TPW; ++u) bn[u] = *(const half8_t*)(bp[u] + kn);
            }
            const half8_t a0 = *(const half8_t*)(wlds + ((size_t)(kb * 64 + lane)) * 8);
            const half8_t a1 = *(const half8_t*)(wlds + 32768 + ((size_t)(kb * 64 + lane)) * 8);
            #pragma unroll
            for (int u = 0; u < TPW; ++u) {
                acc[u][0] = __builtin_amdgcn_mfma_f32_16x16x32_f16(a0, bc[u], acc[u][0], 0, 0, 0);
                acc[u][1] = __builtin_amdgcn_mfma_f32_16x16x32_f16(a1, bc[u], acc[u][1], 0, 0, 0);
            }
            #pragma unroll
            for (int u = 0; u < TPW; ++u) bc[u] = bn[u];
        }
        // store: C row(n)=quad*4+r, col(m)=mi -> octet-blocked I
        #pragma unroll
        for (int s = 0; s < 2; ++s) {
            const int n0 = row_base + s * 16 + quad * 4;
            const size_t obase = (size_t)(n0 >> 3) * (MTOT * 8) + (n0 & 7);
            #pragma unroll
            for (int u = 0; u < TPW; ++u) {
                if (!val[u]) continue;
                half4_t h;
                #pragma unroll
                for (int r = 0; r < 4; ++r) h[r] = (_Float16)acc[u][s][r];
                *(half4_t*)(I + obase + (size_t)(mt[u] * 16 + mi) * 8) = h;
            }
        }
    }
}

extern "C" void kernel_launch(void* const* d_in, const int* in_sizes, int n_in,
                              void* d_out, int out_size, void* d_ws, size_t ws_size,
                              hipStream_t stream) {
    // setup_inputs() dict order: x, noise, time_steps, W0, b0, W1, b1, W2, b2
    const float* x     = (const float*)d_in[0];
    const float* noise = (const float*)d_in[1];
    const float* W0 = (const float*)d_in[3];
    const float* b0 = (const float*)d_in[4];
    const float* W1 = (const float*)d_in[5];
    const float* b1 = (const float*)d_in[6];
    const float* W2 = (const float*)d_in[7];
    const float* b2 = (const float*)d_in[8];
    float* out = (float*)d_out;

    _Float16* R0 = (_Float16*)((char*)d_ws + R0_OFF);
    _Float16* R1 = (_Float16*)((char*)d_ws + R1_OFF);
    _Float16* Ib = (_Float16*)((char*)d_ws + I_OFF);

    // encode -> R0 ; convW0 -> R1
    snn_enc_convw_kernel<<<dim3(456), dim3(256), 0, stream>>>(x, noise, R0, out, W0, R1);
    // gemm0: 32 nbb x 8 chunks = 256 blocks (64-row)
    snn_gemm64_kernel<8><<<dim3(256), dim3(1024), 0, stream>>>(R1, R0, Ib);
    // scan0 (I->R1, 256 blocks) ; convW1 -> R0 (256 blocks)
    snn_scan_convw_kernel<<<dim3(512), dim3(256), 0, stream>>>(Ib, b0, R1, out, 256, 11, W1, R0);
    // gemm1
    snn_gemm64_kernel<8><<<dim3(256), dim3(1024), 0, stream>>>(R0, R1, Ib);
    // scan1 (I->R0, 256 blocks) ; convW2 -> R1 (64 blocks)
    snn_scan_convw_kernel<<<dim3(320), dim3(256), 0, stream>>>(Ib, b1, R0, out, 256, 11, W2, R1);
    // gemm2: 16 nbb x 16 chunks = 256 blocks, 1 tile/wave (32-row, R9)
    snn_gemm_kernel<16, 1><<<dim3(256), dim3(1024), 0, stream>>>(R1, R0, Ib);
    // scan2 -> out
    snn_scan_kernel<<<dim3(64), dim3(256), 0, stream>>>(Ib, b2, out, 9);

    (void)in_sizes; (void)n_in; (void)out_size; (void)ws_size;
}